// Round 3
// baseline (432.652 us; speedup 1.0000x reference)
//
#include <hip/hip_runtime.h>
#include <math.h>

// SimpleGCN R15.
//  - R14 post-mortem: (a) 800k same-line global fp32 atomics in agg_pool =
//    +110us -> reverted to pbuf + k_mean_final (R12-measured path).
//    (b) per-wave VGPR W2 (wcol) = 4x16KB W2 L1 re-reads per block (~20us)
//    -> reverted to cooperative LDS Ws staging.
//  - New: 2 nodes per wave in both agg kernels (lane=(h,q,c), 8 nodes/block,
//    6250 blocks). Two independent gather chains interleave per wave
//    (latency hiding), wave count halves, epilogue Ws reads serve 2 nodes.
//    k_agg_fuse: hs is wave-local -> no post-park barrier (one barrier after
//    Ws staging only). k_agg_pool keeps its cross-wave barrier.
//  - Preprocessing: direct CSR (memsetAsync(deg) -> k_deg atomics ->
//    k_scan2 1-block prefix (+dinv,+cur,+g=0) -> k_scatter2 atomics).
//    Replaces hist/scan/scatter/local_sort. csr is int32 now.
//  - 8 kernels + 1 memset.

__device__ __forceinline__ float bf2f(unsigned short u) {
    return __uint_as_float(((unsigned)u) << 16);
}
__device__ __forceinline__ unsigned short f2bf(float x) {
    unsigned b = __float_as_uint(x);
    return (unsigned short)((b + 0x7FFF + ((b >> 16) & 1)) >> 16);  // RNE
}

// deg[d] += 1 per edge. deg pre-zeroed by hipMemsetAsync.
__global__ __launch_bounds__(256) void k_deg(const int* __restrict__ dst,
                                             int* __restrict__ deg, int E) {
    int i = blockIdx.x * 256 + threadIdx.x;
    int stride = gridDim.x * 256;
    for (int e = i; e < E; e += stride) atomicAdd(&deg[dst[e]], 1);
}

// ONE block, 1024 threads: exclusive prefix of deg -> offsets, cursor copy,
// dinv = (deg+1)^-0.5, zero g. Thread t owns a contiguous chunk of C nodes.
__global__ __launch_bounds__(1024) void k_scan2(const int* __restrict__ deg,
                                                int* __restrict__ offsets,
                                                int* __restrict__ cur,
                                                float* __restrict__ dinv,
                                                float* __restrict__ g,
                                                int n, int E) {
    __shared__ int sc[1024];
    int t = threadIdx.x;
    int C = (n + 1023) / 1024;
    int base = t * C;
    int lim = base + C; if (lim > n) lim = n;
    int sum = 0;
    for (int i = base; i < lim; i++) sum += deg[i];
    sc[t] = sum;
    __syncthreads();
    for (int off = 1; off < 1024; off <<= 1) {
        int x = (t >= off) ? sc[t - off] : 0;
        __syncthreads();
        sc[t] += x;
        __syncthreads();
    }
    int run = sc[t] - sum;  // exclusive
    for (int i = base; i < lim; i++) {
        int d = deg[i];
        offsets[i] = run;
        cur[i] = run;
        dinv[i] = 1.0f / sqrtf((float)(d + 1));  // + self-loop
        run += d;
    }
    if (t == 0) offsets[n] = E;
    if (t < 64) g[t] = 0.f;
}

// csr[cur[dst]++] = src  (node-contiguous CSR; order within node irrelevant).
__global__ __launch_bounds__(256) void k_scatter2(const int* __restrict__ src,
                                                  const int* __restrict__ dst,
                                                  int* __restrict__ cur,
                                                  int* __restrict__ csr, int E) {
    int i = blockIdx.x * 256 + threadIdx.x;
    int stride = gridDim.x * 256;
    for (int e = i; e < E; e += stride) {
        int d = dst[e];
        int pos = atomicAdd(&cur[d], 1);
        csr[pos] = src[e];
    }
}

// y1[i,:] = dinv[i] * (X[i,:] @ W) stored as bf16 rows (128B = 1 line).
__global__ __launch_bounds__(256) void k_gemm_scale(const float* __restrict__ X,
                                                    const float* __restrict__ W,
                                                    const float* __restrict__ dinv,
                                                    unsigned short* __restrict__ Y, int n) {
    __shared__ float Ws[64 * 64];
    __shared__ float xs[16][64];
    int t = threadIdx.x, w = t >> 6, f = t & 63;
    const float4* W4 = (const float4*)W;
    float4* Ws4 = (float4*)Ws;
#pragma unroll
    for (int j = 0; j < 4; j++) Ws4[t + 256 * j] = W4[t + 256 * j];
    int r0 = blockIdx.x * 16;
#pragma unroll
    for (int i = 0; i < 4; i++) {
        int r = r0 + w * 4 + i;
        xs[w * 4 + i][f] = (r < n) ? X[(size_t)r * 64 + f] : 0.f;
    }
    __syncthreads();
    float acc[4] = {0.f, 0.f, 0.f, 0.f};
#pragma unroll 8
    for (int k = 0; k < 64; k++) {
        float wv = Ws[k * 64 + f];
#pragma unroll
        for (int i = 0; i < 4; i++) acc[i] += xs[w * 4 + i][k] * wv;
    }
#pragma unroll
    for (int i = 0; i < 4; i++) {
        int r = r0 + w * 4 + i;
        if (r < n) Y[(size_t)r * 64 + f] = f2bf(dinv[r] * acc[i]);
    }
}

// Layer-1 aggregate + fused GEMM2, 2 nodes per wave.
// lane = (h,q,c): h = node half (bit5), q = edge slot (bit4), c = feat quad.
// Slot q covers edge residues 4q..4q+3 mod 8; ushort4 row loads (16 lanes c
// = one 128B y1 row), same gather instruction shape as R12 (4 rows/instr).
// Reduce = single shfl_xor(16) (q-pair within each half).
// Epilogue per wave: 64 Ws b32 reads serve BOTH nodes (2x128 FMA).
__global__ __launch_bounds__(256) void k_agg_fuse(const unsigned short* __restrict__ Y,
                                                  const float* __restrict__ dinv,
                                                  const float* __restrict__ bias,
                                                  const int* __restrict__ offsets,
                                                  const int* __restrict__ csr,
                                                  const float* __restrict__ W2,
                                                  unsigned short* __restrict__ Yout, int n) {
    __shared__ float Ws[64 * 64];   // 16 KB
    __shared__ float hs[8][64];     // 2 KB
    const ushort4* Y4 = (const ushort4*)Y;
    int t = threadIdx.x, w = t >> 6, l = t & 63;
    int h = l >> 5, q = (l >> 4) & 1, c = l & 15;
    {
        const float4* W4 = (const float4*)W2;
        float4* Ws4 = (float4*)Ws;
#pragma unroll
        for (int j = 0; j < 4; j++) Ws4[t + 256 * j] = W4[t + 256 * j];
    }
    __syncthreads();  // Ws visible to all waves; hs needs no barrier (wave-local)
    int node = blockIdx.x * 8 + w * 2 + h;
    bool valid = node < n;
    float4 hval = make_float4(0.f, 0.f, 0.f, 0.f);
    if (valid) {
        float4 acc = make_float4(0.f, 0.f, 0.f, 0.f);
        if (q == 0) {  // self-loop term
            ushort4 u = Y4[(size_t)node * 16 + c];
            acc = make_float4(bf2f(u.x), bf2f(u.y), bf2f(u.z), bf2f(u.w));
        }
        int beg = offsets[node], end = offsets[node + 1];
        for (int j = beg + q * 4; j < end; j += 8) {
#pragma unroll
            for (int u = 0; u < 4; u++) {
                int jj = j + u;
                if (jj < end) {
                    int s = csr[jj];                     // uniform within slot
                    ushort4 v = Y4[(size_t)s * 16 + c];  // 16 lanes x 8B = row
                    acc.x += bf2f(v.x); acc.y += bf2f(v.y);
                    acc.z += bf2f(v.z); acc.w += bf2f(v.w);
                }
            }
        }
        acc.x += __shfl_xor(acc.x, 16);
        acc.y += __shfl_xor(acc.y, 16);
        acc.z += __shfl_xor(acc.z, 16);
        acc.w += __shfl_xor(acc.w, 16);
        float dv = dinv[node];
        float4 b4 = ((const float4*)bias)[c];
        hval.x = fmaxf(dv * acc.x + b4.x, 0.f);
        hval.y = fmaxf(dv * acc.y + b4.y, 0.f);
        hval.z = fmaxf(dv * acc.z + b4.z, 0.f);
        hval.w = fmaxf(dv * acc.w + b4.w, 0.f);
    }
    if (q == 0) ((float4*)hs[w * 2 + h])[c] = hval;  // zeros if invalid
    // wave-local LDS RAW: DS ops from one wave complete in program order.
    float acc2a = 0.f, acc2b = 0.f;
#pragma unroll
    for (int m = 0; m < 16; m++) {
        float4 ha = ((const float4*)hs[w * 2 + 0])[m];   // wave-broadcast
        float4 hb = ((const float4*)hs[w * 2 + 1])[m];
        float wv0 = Ws[(4 * m + 0) * 64 + l];
        float wv1 = Ws[(4 * m + 1) * 64 + l];
        float wv2 = Ws[(4 * m + 2) * 64 + l];
        float wv3 = Ws[(4 * m + 3) * 64 + l];
        acc2a += ha.x * wv0 + ha.y * wv1 + ha.z * wv2 + ha.w * wv3;
        acc2b += hb.x * wv0 + hb.y * wv1 + hb.z * wv2 + hb.w * wv3;
    }
    int nodeA = blockIdx.x * 8 + w * 2;
    int nodeB = nodeA + 1;
    if (nodeA < n) Yout[(size_t)nodeA * 64 + l] = f2bf(dinv[nodeA] * acc2a);
    if (nodeB < n) Yout[(size_t)nodeB * 64 + l] = f2bf(dinv[nodeB] * acc2b);
}

// Layer-2 aggregate + per-block partial mean row (pbuf path, R12-measured).
__global__ __launch_bounds__(256) void k_agg_pool(const unsigned short* __restrict__ Y,
                                                  const float* __restrict__ dinv,
                                                  const float* __restrict__ bias,
                                                  const int* __restrict__ offsets,
                                                  const int* __restrict__ csr,
                                                  float* __restrict__ pbuf, int n) {
    __shared__ float4 sm4[8][16];
    const ushort4* Y4 = (const ushort4*)Y;
    int t = threadIdx.x, w = t >> 6, l = t & 63;
    int h = l >> 5, q = (l >> 4) & 1, c = l & 15;
    int node = blockIdx.x * 8 + w * 2 + h;
    bool valid = node < n;
    float4 hval = make_float4(0.f, 0.f, 0.f, 0.f);
    if (valid) {
        float4 acc = make_float4(0.f, 0.f, 0.f, 0.f);
        if (q == 0) {
            ushort4 u = Y4[(size_t)node * 16 + c];
            acc = make_float4(bf2f(u.x), bf2f(u.y), bf2f(u.z), bf2f(u.w));
        }
        int beg = offsets[node], end = offsets[node + 1];
        for (int j = beg + q * 4; j < end; j += 8) {
#pragma unroll
            for (int u = 0; u < 4; u++) {
                int jj = j + u;
                if (jj < end) {
                    int s = csr[jj];
                    ushort4 v = Y4[(size_t)s * 16 + c];
                    acc.x += bf2f(v.x); acc.y += bf2f(v.y);
                    acc.z += bf2f(v.z); acc.w += bf2f(v.w);
                }
            }
        }
        acc.x += __shfl_xor(acc.x, 16);
        acc.y += __shfl_xor(acc.y, 16);
        acc.z += __shfl_xor(acc.z, 16);
        acc.w += __shfl_xor(acc.w, 16);
        float dv = dinv[node];
        float4 b4 = ((const float4*)bias)[c];
        hval.x = fmaxf(dv * acc.x + b4.x, 0.f);
        hval.y = fmaxf(dv * acc.y + b4.y, 0.f);
        hval.z = fmaxf(dv * acc.z + b4.z, 0.f);
        hval.w = fmaxf(dv * acc.w + b4.w, 0.f);
    }
    if (q == 0) sm4[w * 2 + h][c] = hval;  // zeros if invalid
    __syncthreads();
    if (t < 16) {
        float4 s = make_float4(0.f, 0.f, 0.f, 0.f);
#pragma unroll
        for (int r = 0; r < 8; r++) {
            float4 a = sm4[r][t];
            s.x += a.x; s.y += a.y; s.z += a.z; s.w += a.w;
        }
        ((float4*)pbuf)[(size_t)blockIdx.x * 16 + t] = s;
    }
}

__global__ void k_mean_final(const float* __restrict__ pbuf, float* __restrict__ g,
                             int nrows) {
    __shared__ float part[256];
    int t = threadIdx.x, w = t >> 6, f = t & 63;
    float local = 0.f;
    for (int r = blockIdx.x * 4 + w; r < nrows; r += gridDim.x * 4)
        local += pbuf[(size_t)r * 64 + f];
    part[t] = local;
    __syncthreads();
    if (w == 0) {
        float tot = part[f] + part[64 + f] + part[128 + f] + part[192 + f];
        atomicAdd(&g[f], tot);
    }
}

__global__ void k_readout(const float* __restrict__ g, const float* __restrict__ Wr,
                          const float* __restrict__ br, float* __restrict__ out,
                          float invn) {
    __shared__ float gl[64];
    int t = threadIdx.x;
    if (t < 64) gl[t] = g[t] * invn;
    __syncthreads();
    float acc = br[t];
#pragma unroll
    for (int k = 0; k < 64; k++) acc += gl[k] * Wr[k * 128 + t];
    out[t] = acc;
}

extern "C" void kernel_launch(void* const* d_in, const int* in_sizes, int n_in,
                              void* d_out, int out_size, void* d_ws, size_t ws_size,
                              hipStream_t stream) {
    const float* x  = (const float*)d_in[0];
    const int*   ei = (const int*)d_in[1];   // int32 on device (JAX x64 off)
    const float* W1 = (const float*)d_in[2];
    const float* b1 = (const float*)d_in[3];
    const float* W2 = (const float*)d_in[4];
    const float* b2 = (const float*)d_in[5];
    const float* Wr = (const float*)d_in[6];
    const float* br = (const float*)d_in[7];
    float* out = (float*)d_out;

    int n = in_sizes[0] / 64;   // 50000
    int E = in_sizes[1] / 2;    // 800000
    const int* src = ei;
    const int* dst = ei + E;

    int gb = (n + 7) / 8;       // 6250 aggregate blocks (2 nodes per wave)

    // workspace layout (~19 MB)
    char* p = (char*)d_ws;
    unsigned short* y1 = (unsigned short*)p; p += (size_t)n * 64 * sizeof(unsigned short);
    unsigned short* y2 = (unsigned short*)p; p += (size_t)n * 64 * sizeof(unsigned short);
    float* pbuf = (float*)p;   p += (size_t)gb * 64 * sizeof(float);
    float* dinv = (float*)p;   p += (size_t)n * sizeof(float);
    float* g = (float*)p;      p += 64 * sizeof(float);
    int* deg = (int*)p;        p += (size_t)n * sizeof(int);
    int* cur = (int*)p;        p += (size_t)n * sizeof(int);
    int* offsets = (int*)p;    p += (size_t)(n + 1) * sizeof(int);
    int* csr = (int*)p;        p += (size_t)E * sizeof(int);

    hipMemsetAsync(deg, 0, (size_t)n * sizeof(int), stream);
    k_deg<<<1024, 256, 0, stream>>>(dst, deg, E);
    k_scan2<<<1, 1024, 0, stream>>>(deg, offsets, cur, dinv, g, n, E);
    k_scatter2<<<1024, 256, 0, stream>>>(src, dst, cur, csr, E);

    k_gemm_scale<<<(n + 15) / 16, 256, 0, stream>>>(x, W1, dinv, y1, n);
    k_agg_fuse<<<gb, 256, 0, stream>>>(y1, dinv, b1, offsets, csr, W2, y2, n);
    k_agg_pool<<<gb, 256, 0, stream>>>(y2, dinv, b2, offsets, csr, pbuf, n);

    k_mean_final<<<64, 256, 0, stream>>>(pbuf, g, gb);
    k_readout<<<1, 128, 0, stream>>>(g, Wr, br, out, 1.0f / (float)n);
}

// Round 5
// 257.135 us; speedup vs baseline: 1.6826x; 1.6826x over previous
//
#include <hip/hip_runtime.h>
#include <math.h>

// SimpleGCN R17 = R12 (measured 230.9us) + ONE isolated delta.
//  - R16 failed with a container-level error (no counters). Risky last-block
//    ticket readout removed; back to R12's k_mean_final + k_readout.
//  - Single delta vs R12: 2 nodes per wave in both agg kernels
//    (lane=(h,q,c): h=node half, q=edge slot, c=feat quad; 8 nodes/block,
//    6250 blocks). Two independent csr->row gather chains per wave (R12 was
//    VALUBusy 36% = latency-bound on one chain); epilogue Ws b32 reads are
//    shared by both nodes; hs rows wave-local -> post-park barrier dropped
//    in k_agg_fuse (same-wave DS ordering via lgkmcnt).
//  - Preprocessing (hist/scan/scatter/local_sort, ushort csr), gemm_scale,
//    mean_final, readout: R12 verbatim. 9 dispatches.

#define CH 4096    // edges per chunk-block in hist/scatter
#define MAXNB 1024 // NB = ceil(n/64) <= 1024 (n <= 65536)

__device__ __forceinline__ float bf2f(unsigned short u) {
    return __uint_as_float(((unsigned)u) << 16);
}
__device__ __forceinline__ unsigned short f2bf(float x) {
    unsigned b = __float_as_uint(x);
    return (unsigned short)((b + 0x7FFF + ((b >> 16) & 1)) >> 16);  // RNE
}

__global__ __launch_bounds__(256) void k_bucket_hist(const int* __restrict__ dst,
                                                     int* __restrict__ histmat,
                                                     int E, int NB) {
    __shared__ int ih[MAXNB];
    int t = threadIdx.x;
    for (int k = t; k < NB; k += 256) ih[k] = 0;
    __syncthreads();
    int base = blockIdx.x * CH;
    for (int i = 0; i < CH; i += 256) {
        int e = base + i + t;
        if (e < E) atomicAdd(&ih[dst[e] >> 6], 1);
    }
    __syncthreads();
    for (int k = t; k < NB; k += 256) histmat[(size_t)blockIdx.x * NB + k] = ih[k];
}

// ONE block, 1024 threads (thread = bucket, NB<=1024): per-bucket exclusive
// prefix over chunks (in-place in histmat, coalesced, unroll-8), then an
// in-LDS Hillis-Steele scan of bucket totals -> bstart. Also zeroes g.
__global__ __launch_bounds__(1024) void k_scan(int* __restrict__ histmat,
                                               int* __restrict__ bstart,
                                               int* __restrict__ offsets,
                                               float* __restrict__ g,
                                               int NB, int nch, int E, int n) {
    __shared__ int sc[1024];
    int t = threadIdx.x;
    int run = 0;
    if (t < NB) {
        int b = 0;
        for (; b + 8 <= nch; b += 8) {
            int v[8];
#pragma unroll
            for (int u = 0; u < 8; u++) v[u] = histmat[(size_t)(b + u) * NB + t];
#pragma unroll
            for (int u = 0; u < 8; u++) {
                int x = v[u];
                histmat[(size_t)(b + u) * NB + t] = run;
                run += x;
            }
        }
        for (; b < nch; b++) {
            int x = histmat[(size_t)b * NB + t];
            histmat[(size_t)b * NB + t] = run;
            run += x;
        }
    }
    sc[t] = (t < NB) ? run : 0;
    __syncthreads();
    for (int off = 1; off < 1024; off <<= 1) {
        int x = (t >= off) ? sc[t - off] : 0;
        __syncthreads();
        sc[t] += x;
        __syncthreads();
    }
    if (t < NB) bstart[t] = sc[t] - run;  // exclusive
    if (t == 0) { bstart[NB] = E; offsets[n] = E; }
    if (t < 64) g[t] = 0.f;
}

__global__ __launch_bounds__(256) void k_bucket_scatter(const int* __restrict__ src,
                                                        const int* __restrict__ dst,
                                                        const int* __restrict__ histmat,
                                                        const int* __restrict__ bstart,
                                                        int* __restrict__ staged,
                                                        int E, int NB) {
    __shared__ int cur[MAXNB];
    int t = threadIdx.x;
    for (int k = t; k < NB; k += 256)
        cur[k] = bstart[k] + histmat[(size_t)blockIdx.x * NB + k];
    __syncthreads();
    int base = blockIdx.x * CH;
    for (int i = 0; i < CH; i += 256) {
        int e = base + i + t;
        if (e < E) {
            int d = dst[e];
            int pos = atomicAdd(&cur[d >> 6], 1);
            staged[pos] = (src[e] << 6) | (d & 63);  // n<=65536 -> fits
        }
    }
}

// one block per bucket: counting-sort staged run into node-granular ushort
// CSR; emit per-node offsets + dinv.
__global__ __launch_bounds__(256) void k_local_sort(const int* __restrict__ staged,
                                                    const int* __restrict__ bstart,
                                                    unsigned short* __restrict__ csr,
                                                    int* __restrict__ offsets,
                                                    float* __restrict__ dinv, int n) {
    __shared__ int cnt[64];
    __shared__ int pos[64];
    __shared__ int cur[64];
    int t = threadIdx.x;
    if (t < 64) cnt[t] = 0;
    __syncthreads();
    int k = blockIdx.x;
    int beg = bstart[k], end = bstart[k + 1];
    for (int e = beg + t; e < end; e += 256) atomicAdd(&cnt[staged[e] & 63], 1);
    __syncthreads();
    if (t == 0) {
        int run = 0;
        for (int i = 0; i < 64; i++) { pos[i] = run; run += cnt[i]; }
    }
    __syncthreads();
    if (t < 64) {
        cur[t] = pos[t];
        int node = k * 64 + t;
        if (node < n) {
            offsets[node] = beg + pos[t];
            dinv[node] = 1.0f / sqrtf((float)(cnt[t] + 1));  // + self-loop
        }
    }
    __syncthreads();
    for (int e = beg + t; e < end; e += 256) {
        int pk = staged[e];
        int p = atomicAdd(&cur[pk & 63], 1);
        csr[beg + p] = (unsigned short)(pk >> 6);
    }
}

// y1[i,:] = dinv[i] * (X[i,:] @ W) stored as bf16 rows (128B = 1 line).
__global__ __launch_bounds__(256) void k_gemm_scale(const float* __restrict__ X,
                                                    const float* __restrict__ W,
                                                    const float* __restrict__ dinv,
                                                    unsigned short* __restrict__ Y, int n) {
    __shared__ float Ws[64 * 64];
    __shared__ float xs[16][64];
    int t = threadIdx.x, w = t >> 6, f = t & 63;
    const float4* W4 = (const float4*)W;
    float4* Ws4 = (float4*)Ws;
#pragma unroll
    for (int j = 0; j < 4; j++) Ws4[t + 256 * j] = W4[t + 256 * j];
    int r0 = blockIdx.x * 16;
#pragma unroll
    for (int i = 0; i < 4; i++) {
        int r = r0 + w * 4 + i;
        xs[w * 4 + i][f] = (r < n) ? X[(size_t)r * 64 + f] : 0.f;
    }
    __syncthreads();
    float acc[4] = {0.f, 0.f, 0.f, 0.f};
#pragma unroll 8
    for (int k = 0; k < 64; k++) {
        float wv = Ws[k * 64 + f];
#pragma unroll
        for (int i = 0; i < 4; i++) acc[i] += xs[w * 4 + i][k] * wv;
    }
#pragma unroll
    for (int i = 0; i < 4; i++) {
        int r = r0 + w * 4 + i;
        if (r < n) Y[(size_t)r * 64 + f] = f2bf(dinv[r] * acc[i]);
    }
}

// Layer-1 aggregate + fused GEMM2, 2 nodes per wave.
// lane = (h,q,c): h = node half (bit5), q = edge slot (bit4), c = feat quad.
// Slot q covers edge positions {4q..4q+3} mod 8 of its node's csr range;
// ushort4 row loads (16 lanes c = one 128B y1 row). Reduce = one
// shfl_xor(16) (q-pair within each half). hs rows are wave-local -> no
// barrier after park; one barrier after Ws staging. Epilogue: 64 Ws b32
// reads per wave serve BOTH nodes (2x64 FMA).
__global__ __launch_bounds__(256) void k_agg_fuse(const unsigned short* __restrict__ Y,
                                                  const float* __restrict__ dinv,
                                                  const float* __restrict__ bias,
                                                  const int* __restrict__ offsets,
                                                  const unsigned short* __restrict__ csr,
                                                  const float* __restrict__ W2,
                                                  unsigned short* __restrict__ Yout, int n) {
    __shared__ float Ws[64 * 64];   // 16 KB
    __shared__ float hs[8][64];     // 2 KB
    const ushort4* Y4 = (const ushort4*)Y;
    int t = threadIdx.x, w = t >> 6, l = t & 63;
    int h = l >> 5, q = (l >> 4) & 1, c = l & 15;
    {
        const float4* W4 = (const float4*)W2;
        float4* Ws4 = (float4*)Ws;
#pragma unroll
        for (int j = 0; j < 4; j++) Ws4[t + 256 * j] = W4[t + 256 * j];
    }
    __syncthreads();  // Ws visible to all waves
    int node = blockIdx.x * 8 + w * 2 + h;
    bool valid = node < n;
    float4 hval = make_float4(0.f, 0.f, 0.f, 0.f);
    if (valid) {
        float4 acc = make_float4(0.f, 0.f, 0.f, 0.f);
        if (q == 0) {  // self-loop term
            ushort4 u = Y4[(size_t)node * 16 + c];
            acc = make_float4(bf2f(u.x), bf2f(u.y), bf2f(u.z), bf2f(u.w));
        }
        int beg = offsets[node], end = offsets[node + 1];
        for (int j = beg + q * 4; j < end; j += 8) {
#pragma unroll
            for (int u = 0; u < 4; u++) {
                int jj = j + u;
                if (jj < end) {
                    int s = csr[jj];                     // uniform within slot
                    ushort4 v = Y4[(size_t)s * 16 + c];  // 16 lanes x 8B = row
                    acc.x += bf2f(v.x); acc.y += bf2f(v.y);
                    acc.z += bf2f(v.z); acc.w += bf2f(v.w);
                }
            }
        }
        acc.x += __shfl_xor(acc.x, 16);
        acc.y += __shfl_xor(acc.y, 16);
        acc.z += __shfl_xor(acc.z, 16);
        acc.w += __shfl_xor(acc.w, 16);
        float dv = dinv[node];
        float4 b4 = ((const float4*)bias)[c];
        hval.x = fmaxf(dv * acc.x + b4.x, 0.f);
        hval.y = fmaxf(dv * acc.y + b4.y, 0.f);
        hval.z = fmaxf(dv * acc.z + b4.z, 0.f);
        hval.w = fmaxf(dv * acc.w + b4.w, 0.f);
    }
    if (q == 0) ((float4*)hs[w * 2 + h])[c] = hval;  // zeros if invalid
    // wave-local LDS RAW: compiler orders via lgkmcnt; no __syncthreads.
    float acc2a = 0.f, acc2b = 0.f;
#pragma unroll
    for (int m = 0; m < 16; m++) {
        float4 ha = ((const float4*)hs[w * 2 + 0])[m];   // wave-broadcast
        float4 hb = ((const float4*)hs[w * 2 + 1])[m];
        float wv0 = Ws[(4 * m + 0) * 64 + l];
        float wv1 = Ws[(4 * m + 1) * 64 + l];
        float wv2 = Ws[(4 * m + 2) * 64 + l];
        float wv3 = Ws[(4 * m + 3) * 64 + l];
        acc2a += ha.x * wv0 + ha.y * wv1 + ha.z * wv2 + ha.w * wv3;
        acc2b += hb.x * wv0 + hb.y * wv1 + hb.z * wv2 + hb.w * wv3;
    }
    int nodeA = blockIdx.x * 8 + w * 2;
    int nodeB = nodeA + 1;
    if (nodeA < n) Yout[(size_t)nodeA * 64 + l] = f2bf(dinv[nodeA] * acc2a);
    if (nodeB < n) Yout[(size_t)nodeB * 64 + l] = f2bf(dinv[nodeB] * acc2b);
}

// Layer-2 aggregate + per-block partial mean row (pbuf path), 2 nodes/wave.
__global__ __launch_bounds__(256) void k_agg_pool(const unsigned short* __restrict__ Y,
                                                  const float* __restrict__ dinv,
                                                  const float* __restrict__ bias,
                                                  const int* __restrict__ offsets,
                                                  const unsigned short* __restrict__ csr,
                                                  float* __restrict__ pbuf, int n) {
    __shared__ float4 sm4[8][16];
    const ushort4* Y4 = (const ushort4*)Y;
    int t = threadIdx.x, w = t >> 6, l = t & 63;
    int h = l >> 5, q = (l >> 4) & 1, c = l & 15;
    int node = blockIdx.x * 8 + w * 2 + h;
    bool valid = node < n;
    float4 hval = make_float4(0.f, 0.f, 0.f, 0.f);
    if (valid) {
        float4 acc = make_float4(0.f, 0.f, 0.f, 0.f);
        if (q == 0) {
            ushort4 u = Y4[(size_t)node * 16 + c];
            acc = make_float4(bf2f(u.x), bf2f(u.y), bf2f(u.z), bf2f(u.w));
        }
        int beg = offsets[node], end = offsets[node + 1];
        for (int j = beg + q * 4; j < end; j += 8) {
#pragma unroll
            for (int u = 0; u < 4; u++) {
                int jj = j + u;
                if (jj < end) {
                    int s = csr[jj];
                    ushort4 v = Y4[(size_t)s * 16 + c];
                    acc.x += bf2f(v.x); acc.y += bf2f(v.y);
                    acc.z += bf2f(v.z); acc.w += bf2f(v.w);
                }
            }
        }
        acc.x += __shfl_xor(acc.x, 16);
        acc.y += __shfl_xor(acc.y, 16);
        acc.z += __shfl_xor(acc.z, 16);
        acc.w += __shfl_xor(acc.w, 16);
        float dv = dinv[node];
        float4 b4 = ((const float4*)bias)[c];
        hval.x = fmaxf(dv * acc.x + b4.x, 0.f);
        hval.y = fmaxf(dv * acc.y + b4.y, 0.f);
        hval.z = fmaxf(dv * acc.z + b4.z, 0.f);
        hval.w = fmaxf(dv * acc.w + b4.w, 0.f);
    }
    if (q == 0) sm4[w * 2 + h][c] = hval;  // zeros if invalid
    __syncthreads();
    if (t < 16) {
        float4 s = make_float4(0.f, 0.f, 0.f, 0.f);
#pragma unroll
        for (int r = 0; r < 8; r++) {
            float4 a = sm4[r][t];
            s.x += a.x; s.y += a.y; s.z += a.z; s.w += a.w;
        }
        ((float4*)pbuf)[(size_t)blockIdx.x * 16 + t] = s;
    }
}

__global__ void k_mean_final(const float* __restrict__ pbuf, float* __restrict__ g,
                             int nrows) {
    __shared__ float part[256];
    int t = threadIdx.x, w = t >> 6, f = t & 63;
    float local = 0.f;
    for (int r = blockIdx.x * 4 + w; r < nrows; r += gridDim.x * 4)
        local += pbuf[(size_t)r * 64 + f];
    part[t] = local;
    __syncthreads();
    if (w == 0) {
        float tot = part[f] + part[64 + f] + part[128 + f] + part[192 + f];
        atomicAdd(&g[f], tot);
    }
}

__global__ void k_readout(const float* __restrict__ g, const float* __restrict__ Wr,
                          const float* __restrict__ br, float* __restrict__ out,
                          float invn) {
    __shared__ float gl[64];
    int t = threadIdx.x;
    if (t < 64) gl[t] = g[t] * invn;
    __syncthreads();
    float acc = br[t];
#pragma unroll
    for (int k = 0; k < 64; k++) acc += gl[k] * Wr[k * 128 + t];
    out[t] = acc;
}

extern "C" void kernel_launch(void* const* d_in, const int* in_sizes, int n_in,
                              void* d_out, int out_size, void* d_ws, size_t ws_size,
                              hipStream_t stream) {
    const float* x  = (const float*)d_in[0];
    const int*   ei = (const int*)d_in[1];   // int32 on device (JAX x64 off)
    const float* W1 = (const float*)d_in[2];
    const float* b1 = (const float*)d_in[3];
    const float* W2 = (const float*)d_in[4];
    const float* b2 = (const float*)d_in[5];
    const float* Wr = (const float*)d_in[6];
    const float* br = (const float*)d_in[7];
    float* out = (float*)d_out;

    int n = in_sizes[0] / 64;   // 50000
    int E = in_sizes[1] / 2;    // 800000
    const int* src = ei;
    const int* dst = ei + E;

    int NB  = (n + 63) / 64;       // 782 buckets of 64 nodes
    int nch = (E + CH - 1) / CH;   // 196 chunks
    int gb  = (n + 7) / 8;         // 6250 aggregate blocks (2 nodes/wave)

    // workspace layout (~19 MB)
    char* p = (char*)d_ws;
    unsigned short* y1 = (unsigned short*)p; p += (size_t)n * 64 * sizeof(unsigned short);
    unsigned short* y2 = (unsigned short*)p; p += (size_t)n * 64 * sizeof(unsigned short);
    float* pbuf = (float*)p;   p += (size_t)gb * 64 * sizeof(float);
    float* dinv = (float*)p;   p += (size_t)n * sizeof(float);
    float* g = (float*)p;      p += 64 * sizeof(float);
    int* staged = (int*)p;     p += (size_t)E * sizeof(int);
    int* offsets = (int*)p;    p += (size_t)(n + 1) * sizeof(int);
    int* histmat = (int*)p;    p += (size_t)nch * NB * sizeof(int);
    int* bstart = (int*)p;     p += (size_t)(NB + 1) * sizeof(int);
    unsigned short* csr = (unsigned short*)p; p += (size_t)E * sizeof(unsigned short);

    k_bucket_hist<<<nch, 256, 0, stream>>>(dst, histmat, E, NB);
    k_scan<<<1, 1024, 0, stream>>>(histmat, bstart, offsets, g, NB, nch, E, n);
    k_bucket_scatter<<<nch, 256, 0, stream>>>(src, dst, histmat, bstart, staged, E, NB);
    k_local_sort<<<NB, 256, 0, stream>>>(staged, bstart, csr, offsets, dinv, n);

    k_gemm_scale<<<(n + 15) / 16, 256, 0, stream>>>(x, W1, dinv, y1, n);
    k_agg_fuse<<<gb, 256, 0, stream>>>(y1, dinv, b1, offsets, csr, W2, y2, n);
    k_agg_pool<<<gb, 256, 0, stream>>>(y2, dinv, b2, offsets, csr, pbuf, n);

    k_mean_final<<<64, 256, 0, stream>>>(pbuf, g, gb);
    k_readout<<<1, 128, 0, stream>>>(g, Wr, br, out, 1.0f / (float)n);
}